// Round 3
// baseline (177.145 us; speedup 1.0000x reference)
//
#include <hip/hip_runtime.h>
#include <stdint.h>

// Problem constants
#define L_    8192
#define N_    8
#define L2_   2048
#define K_    16

typedef unsigned int uint;
typedef unsigned short ushort;
typedef unsigned long long u64;
typedef __attribute__((ext_vector_type(8))) short bh8;   // 8 bf16 (4 VGPRs)
typedef __attribute__((ext_vector_type(4))) float f32x4; // MFMA C/D

// round-to-nearest-even f32 -> bf16 (monotone)
__device__ __forceinline__ ushort f2b(float f){
  uint u = __float_as_uint(f);
  return (ushort)((u + 0x7FFFu + ((u >> 16) & 1u)) >> 16);
}
// monotone float->uint mapping (handles tiny negative self-distances)
__device__ __forceinline__ uint ford(float f){
  uint u = __float_as_uint(f);
  return u ^ ((uint)((int)u >> 31) | 0x80000000u);
}
// inverse of ford
__device__ __forceinline__ float unford(uint u){
  uint v = (u & 0x80000000u) ? (u ^ 0x80000000u) : ~u;
  return __uint_as_float(v);
}

__device__ __forceinline__ void ld8(float* t, const float* p){
  float4 a = *(const float4*)p; float4 b = *(const float4*)(p + 4);
  t[0]=a.x; t[1]=a.y; t[2]=a.z; t[3]=a.w; t[4]=b.x; t[5]=b.y; t[6]=b.z; t[7]=b.w;
}
__device__ __forceinline__ bh8 pack8(const float* v){
  bh8 r;
  #pragma unroll
  for (int j = 0; j < 8; ++j) r[j] = (short)f2b(v[j]);
  return r;
}

// ---------------- K0: prep (cF, keep_coords) + weight pre-pack ----------------
// blocks [0,96): pack w1 (8192) + w2 (16384) f32 -> bf16, 1 elem/thread
// blocks [96,352): cF build. blocks [352,544): keep_coords gather.
__global__ __launch_bounds__(256) void prep_pack_k(const float* __restrict__ coords,
                                                   const int* __restrict__ keep,
                                                   const float* __restrict__ w1,
                                                   const float* __restrict__ w2,
                                                   float4* __restrict__ cF,
                                                   float* __restrict__ out0,
                                                   ushort* __restrict__ pw1,
                                                   ushort* __restrict__ pw2){
  int blk = blockIdx.x;
  int tid = threadIdx.x;
  if (blk < 96){
    int e = blk * 256 + tid;                   // e < 24576 = 8192 + 16384
    if (e < 8192) pw1[e] = f2b(w1[e]);
    else          pw2[e - 8192] = f2b(w2[e - 8192]);
  } else if (blk < 352){
    int e = (blk - 96) * 256 + tid;            // e = l*8+n, e < 65536
    int l = e >> 3, n = e & 7;
    const float* cr = coords + (size_t)e * 3;
    float x = cr[0], y = cr[1], z = cr[2];
    float cc;
    {
      #pragma clang fp contract(off)
      cc = x*x + y*y + z*z;                    // matches np sum(c*c,-1): (xx+yy)+zz
    }
    cF[n * L_ + l] = make_float4(x, y, z, cc);
  } else {
    int t = (blk - 352) * 256 + tid;           // t < 49152 = L2*N*3
    int i = t / 24; int rem = t - i * 24;      // (n*3+c)
    out0[t] = coords[(size_t)keep[i] * 24 + rem];
  }
}

// ---------------- K1: MFMA MLP (pre-packed bf16 weights) ----------------
// grid 256, block 256 = 4 independent waves; wave = 16 rows x 128 dims.
__global__ __launch_bounds__(256) void mlp_k(const float* __restrict__ feat,
                                             const ushort* __restrict__ pw1,
                                             const float* __restrict__ g1,
                                             const float* __restrict__ b1,
                                             const ushort* __restrict__ pw2,
                                             const float* __restrict__ g2,
                                             const float* __restrict__ b2,
                                             uint* __restrict__ fBw){
  __shared__ ushort hlds[64 * 136];            // 17.4 KB; wave wv owns rows [16wv,16wv+16)
  int tid = threadIdx.x;
  int lane = tid & 63;
  int wv = __builtin_amdgcn_readfirstlane(tid >> 6);
  int quad = lane >> 4, c = lane & 15;
  int rowg = blockIdx.x * 64 + wv * 16;        // wave's first row (row = n*2048 + l)

  // A-frags for GEMM1: x[rowg+c][s*32 + quad*8 + j], s=0,1
  bh8 a1[2];
  {
    int rg = rowg + c; int l = rg & 2047, nb = rg >> 11;
    const float* xr = feat + (size_t)((l << 3) + nb) * 64 + quad * 8;
    float t[8];
    ld8(t, xr);      a1[0] = pack8(t);
    ld8(t, xr + 32); a1[1] = pack8(t);
  }

  // GEMM1: h[m][n] = sum_k x[m][k] w1[n][k]
  f32x4 acc1[8];
  #pragma unroll
  for (int t = 0; t < 8; ++t) acc1[t] = (f32x4){0.f, 0.f, 0.f, 0.f};
  #pragma unroll
  for (int s = 0; s < 2; ++s){
    #pragma unroll
    for (int t = 0; t < 8; ++t){
      bh8 wb = *(const bh8*)(pw1 + (size_t)(t * 16 + c) * 64 + s * 32 + quad * 8);
      acc1[t] = __builtin_amdgcn_mfma_f32_16x16x32_bf16(a1[s], wb, acc1[t], 0, 0, 0);
    }
  }

  // LN1 in-register: row m = quad*4+r lives in the 16 lanes of this quad
  float mean1[4], rstd1[4];
  #pragma unroll
  for (int r = 0; r < 4; ++r){
    float s = 0.f;
    #pragma unroll
    for (int t = 0; t < 8; ++t) s += acc1[t][r];
    #pragma unroll
    for (int m = 1; m < 16; m <<= 1) s += __shfl_xor(s, m, 16);
    mean1[r] = s * 0.0078125f;
  }
  #pragma unroll
  for (int r = 0; r < 4; ++r){
    float s = 0.f;
    #pragma unroll
    for (int t = 0; t < 8; ++t){ float d = acc1[t][r] - mean1[r]; s += d * d; }
    #pragma unroll
    for (int m = 1; m < 16; m <<= 1) s += __shfl_xor(s, m, 16);
    rstd1[r] = rsqrtf(s * 0.0078125f + 1e-5f);
  }
  ushort* hl = hlds + wv * 16 * 136;
  #pragma unroll
  for (int t = 0; t < 8; ++t){
    float gv = g1[t * 16 + c], bv = b1[t * 16 + c];
    #pragma unroll
    for (int r = 0; r < 4; ++r){
      float v = (acc1[t][r] - mean1[r]) * rstd1[r] * gv + bv;
      hl[(quad * 4 + r) * 136 + t * 16 + c] = f2b(v);
    }
  }

  // GEMM2: A-frags from LDS (layout transform), B = packed w2
  f32x4 acc2[8];
  #pragma unroll
  for (int t = 0; t < 8; ++t) acc2[t] = (f32x4){0.f, 0.f, 0.f, 0.f};
  #pragma unroll
  for (int s = 0; s < 4; ++s){
    bh8 af = *(const bh8*)(hl + c * 136 + s * 32 + quad * 8);   // 16B-aligned
    #pragma unroll
    for (int t = 0; t < 8; ++t){
      bh8 wb = *(const bh8*)(pw2 + (size_t)(t * 16 + c) * 128 + s * 32 + quad * 8);
      acc2[t] = __builtin_amdgcn_mfma_f32_16x16x32_bf16(af, wb, acc2[t], 0, 0, 0);
    }
  }

  // LN2 + ReLU
  float mean2[4], rstd2[4];
  #pragma unroll
  for (int r = 0; r < 4; ++r){
    float s = 0.f;
    #pragma unroll
    for (int t = 0; t < 8; ++t) s += acc2[t][r];
    #pragma unroll
    for (int m = 1; m < 16; m <<= 1) s += __shfl_xor(s, m, 16);
    mean2[r] = s * 0.0078125f;
  }
  #pragma unroll
  for (int r = 0; r < 4; ++r){
    float s = 0.f;
    #pragma unroll
    for (int t = 0; t < 8; ++t){ float d = acc2[t][r] - mean2[r]; s += d * d; }
    #pragma unroll
    for (int m = 1; m < 16; m <<= 1) s += __shfl_xor(s, m, 16);
    rstd2[r] = rsqrtf(s * 0.0078125f + 1e-5f);
  }
  #pragma unroll
  for (int t = 0; t < 8; ++t){
    float gv = g2[t * 16 + c], bv = b2[t * 16 + c];
    #pragma unroll
    for (int r = 0; r < 4; ++r){
      float v = fmaxf((acc2[t][r] - mean2[r]) * rstd2[r] * gv + bv, 0.f);
      hl[(quad * 4 + r) * 136 + t * 16 + c] = f2b(v);
    }
  }

  // coalesced store: lane -> row16 = lane>>2, dword-chunk = lane&3
  {
    int row16 = lane >> 2, chunk = lane & 3;
    const uint* src = (const uint*)hlds + (wv * 16 + row16) * 68 + chunk * 16;
    uint* dst = fBw + (size_t)(rowg + row16) * 64 + chunk * 16;
    #pragma unroll
    for (int j = 0; j < 4; ++j)
      *(uint4*)(dst + j * 4) = *(const uint4*)(src + j * 4);
  }
}

// ---------------- K2: fused KNN + pool, 4 queries/wave, LDS point tiles ----------------
__device__ __forceinline__ u64 shfl64(u64 v, int src){
  int lo = __shfl((int)(uint)v, src, 64);
  int hi = __shfl((int)(uint)(v >> 32), src, 64);
  return ((u64)(uint)hi << 32) | (uint)lo;
}

__device__ __forceinline__ u64 bsort64(u64 key, int lane){
  #pragma unroll
  for (int k = 2; k <= 64; k <<= 1){
    #pragma unroll
    for (int j = k >> 1; j > 0; j >>= 1){
      u64 o = shfl64(key, lane ^ j);
      bool lower = (lane & j) == 0;
      bool down  = (lane & k) == 0;
      bool takeMin = (lower == down);
      bool oLess = o < key;
      key = (oLess == takeMin) ? o : key;
    }
  }
  return key;
}
__device__ __forceinline__ u64 bmerge64(u64 key, int lane){
  #pragma unroll
  for (int j = 32; j > 0; j >>= 1){
    u64 o = shfl64(key, lane ^ j);
    bool lower = (lane & j) == 0;
    bool oLess = o < key;
    key = (oLess == lower) ? o : key;
  }
  return key;
}

// exact selection (single instantiation): sort queue (<=128), leave top-16 at
// ldsq[0..16), return the per-lane sorted key (lanes 0..15 = top-16 ascending).
__device__ __attribute__((noinline)) u64 drainx(u64* ldsq, int qcount, int lane){
  u64 a = (lane < qcount) ? ldsq[lane] : ~0ull;
  a = bsort64(a, lane);
  if (qcount > 64){
    u64 b = (64 + lane < qcount) ? ldsq[64 + lane] : ~0ull;
    b = bsort64(b, lane);
    u64 br = shfl64(b, 63 - lane);
    a = a < br ? a : br;
    a = bmerge64(a, lane);
  }
  if (lane < 16) ldsq[lane] = a;
  return a;
}

// Cheap valid bound + compaction, fully inline/unrolled, qc <= 128:
//  - m = per-lane min of the (<=2) stripe entries' high words
//  - 16-step coarse MSB ballot search on bits 31..16: v = largest 2^16-aligned
//    value with count(m < v) < 16;  vb = v + 2^16  =>  vb > true 16th smallest
//    (valid screen/keep upper bound; coarse slack ~2^-7 relative)
//  - compact keeping h <= vb (superset of the true top-16; reuses loaded regs)
//  - cold guard (ties pathology): exact drainx reduce to 16
__device__ __forceinline__ void updq(u64* ql, int& qc, int& nx, float& thr,
                                     float qw, int lane){
  int q = qc;
  u64 k0 = (lane < q) ? ql[lane] : ~0ull;
  u64 k1 = (64 + lane < q) ? ql[64 + lane] : ~0ull;
  uint h0 = (uint)(k0 >> 32), h1 = (uint)(k1 >> 32);
  uint m = h0 < h1 ? h0 : h1;
  uint v = 0u;
  #pragma unroll
  for (int b = 31; b >= 16; --b){
    uint tv = v | (1u << b);
    if (__popcll(__ballot(m < tv)) < 16) v = tv;
  }
  uint vb = (v >= 0xFFFF0000u) ? 0xFFFFFFFFu : (v + 0x10000u);

  bool kp0 = (h0 <= vb);                 // absent lanes: h=0xFFFFFFFF -> dropped
  u64 bal0 = __ballot(kp0);
  int r0 = __builtin_amdgcn_mbcnt_lo((uint)bal0, 0);
  r0 = __builtin_amdgcn_mbcnt_hi((uint)(bal0 >> 32), r0);
  if (kp0) ql[r0] = k0;
  int c0 = __popcll(bal0);
  bool kp1 = (h1 <= vb);
  u64 bal1 = __ballot(kp1);
  int r1 = __builtin_amdgcn_mbcnt_lo((uint)bal1, 0);
  r1 = __builtin_amdgcn_mbcnt_hi((uint)(bal1 >> 32), r1);
  if (kp1) ql[c0 + r1] = k1;
  int out = c0 + __popcll(bal1);

  uint hb = vb;
  if (out > 64){                         // cold: tie pathology -> exact reduce
    u64 a = drainx(ql, out, lane);
    hb = (uint)(shfl64(a, 15) >> 32);
    out = 16;
  }
  qc = out;
  nx = out + 33;
  thr = unford(hb) + 1e-3f - qw;
}

// Block = 4 waves, 16 queries (4/wave), one n. Points staged per-block in LDS.
__global__ __launch_bounds__(256) void knn_pool_k(const float4* __restrict__ cF,
                                                  const int* __restrict__ keep,
                                                  const uint* __restrict__ fB32,
                                                  float* __restrict__ out1){
  __shared__ float4 tile[256];          // 4 KB point tile (shared by all 16 queries)
  __shared__ u64 q16[16][128];          // 16 KB survivor queues
  int tid = threadIdx.x, lane = tid & 63;
  int wv = tid >> 6;
  int qbase = blockIdx.x * 16;          // block = 16 queries, one n
  int n = qbase >> 11;
  int i0 = (qbase & 2047) + wv * 4;     // wave's first query within n
  const float4* base = cF + (n << 13);

  u64* ql[4] = { q16[wv * 4 + 0], q16[wv * 4 + 1], q16[wv * 4 + 2], q16[wv * 4 + 3] };
  float4 qv[4];
  float q2x[4], q2y[4], q2z[4], qw4[4], thr[4];
  int qc[4], nx[4];
  #pragma unroll
  for (int qi = 0; qi < 4; ++qi){
    qv[qi] = base[keep[i0 + qi]];
    q2x[qi] = -2.f * qv[qi].x; q2y[qi] = -2.f * qv[qi].y; q2z[qi] = -2.f * qv[qi].z;
    qw4[qi] = qv[qi].w;
    thr[qi] = 3.4e38f; qc[qi] = 0; nx[qi] = 49;
  }

  #define PROC1(qi, cf, jidx) { \
    float s = __builtin_fmaf(q2x[qi],(cf).x, __builtin_fmaf(q2y[qi],(cf).y, \
              __builtin_fmaf(q2z[qi],(cf).z,(cf).w))); \
    u64 bal = __ballot(s <= thr[qi]); \
    if (bal){ \
      if (s <= thr[qi]){ \
        float d2; \
        { \
          _Pragma("clang fp contract(off)") \
          float dot = qv[qi].x*(cf).x + qv[qi].y*(cf).y + qv[qi].z*(cf).z; \
          d2 = (qw4[qi] + (cf).w) - 2.0f * dot; \
        } \
        int rel = __builtin_amdgcn_mbcnt_lo((uint)bal, 0); \
        rel = __builtin_amdgcn_mbcnt_hi((uint)(bal >> 32), rel); \
        ql[qi][qc[qi] + rel] = ((u64)ford(d2) << 32) | (uint)(jidx); \
      } \
      qc[qi] += __popcll(bal); \
      if (qc[qi] >= nx[qi]) updq(ql[qi], qc[qi], nx[qi], thr[qi], qw4[qi], lane); \
    } \
  }

  // tile loop: stage 256 points/iter cooperatively; reg-prefetch next tile
  float4 stage = base[tid];
  for (int t = 0; t < 32; ++t){
    __syncthreads();                    // all waves done reading previous tile
    tile[tid] = stage;
    __syncthreads();                    // tile visible to all waves
    if (t < 31) stage = base[(t + 1) * 256 + tid];   // overlaps processing
    int j0 = t << 8;
    #pragma unroll
    for (int j = 0; j < 4; ++j){
      float4 cf = tile[j * 64 + lane];
      int jj = j0 + j * 64 + lane;
      PROC1(0, cf, jj);
      PROC1(1, cf, jj);
      PROC1(2, cf, jj);
      PROC1(3, cf, jj);
    }
  }
  #undef PROC1

  // final exact selection (u64 order = (dist, idx) tie-break, matches top_k)
  u64 aQ[4];
  #pragma unroll
  for (int qi = 0; qi < 4; ++qi)
    aQ[qi] = drainx(ql[qi], qc[qi], lane);

  const uint* frow = fB32 + ((size_t)(n << 11) << 6);
  float m0[4], m1[4];
  #pragma unroll
  for (int qi = 0; qi < 4; ++qi){ m0[qi] = -3.4e38f; m1[qi] = -3.4e38f; }
  #pragma unroll
  for (int k = 0; k < 16; ++k){
    #pragma unroll
    for (int qi = 0; qi < 4; ++qi){
      int idx = (int)(shfl64(aQ[qi], k) & 2047u);      // fmod(L2) quirk
      uint u = frow[((size_t)idx << 6) + lane];
      m0[qi] = fmaxf(m0[qi], __uint_as_float((u & 0xFFFFu) << 16));
      m1[qi] = fmaxf(m1[qi], __uint_as_float((u >> 16) << 16));
    }
  }
  #pragma unroll
  for (int qi = 0; qi < 4; ++qi){
    float2* o = (float2*)(out1 + (size_t)((i0 + qi) * 8 + n) * 128);
    o[lane] = make_float2(m0[qi], m1[qi]);
  }
}

extern "C" void kernel_launch(void* const* d_in, const int* in_sizes, int n_in,
                              void* d_out, int out_size, void* d_ws, size_t ws_size,
                              hipStream_t stream){
  const float* coords = (const float*)d_in[0];
  const float* feat   = (const float*)d_in[1];
  const float* w1     = (const float*)d_in[2];
  const float* g1     = (const float*)d_in[3];
  const float* b1     = (const float*)d_in[4];
  const float* w2     = (const float*)d_in[5];
  const float* g2     = (const float*)d_in[6];
  const float* b2     = (const float*)d_in[7];
  const int*   keep   = (const int*)d_in[8];
  float* out0 = (float*)d_out;                    // keep_coords [2048,8,3]
  float* out1 = out0 + 49152;                     // pool_features [2048,8,128]

  char* ws = (char*)d_ws;
  float4* cF  = (float4*)ws;                      // [N][L] f32x4 : 1 MB
  ushort* fB  = (ushort*)(ws + (1 << 20));        // [N][L2][128] bf16 : 4 MB
  ushort* pw1 = (ushort*)(ws + (5 << 20));        // 16 KB packed w1
  ushort* pw2 = pw1 + 8192;                       // 32 KB packed w2

  hipLaunchKernelGGL(prep_pack_k, dim3(544), dim3(256), 0, stream,
                     coords, keep, w1, w2, cF, out0, pw1, pw2);
  hipLaunchKernelGGL(mlp_k, dim3(256), dim3(256), 0, stream,
                     feat, pw1, g1, b1, pw2, g2, b2, (uint*)fB);
  hipLaunchKernelGGL(knn_pool_k, dim3(1024), dim3(256), 0, stream,
                     cF, keep, (const uint*)fB, out1);
}

// Round 5
// 158.748 us; speedup vs baseline: 1.1159x; 1.1159x over previous
//
#include <hip/hip_runtime.h>
#include <stdint.h>

// Problem constants
#define L_    8192
#define N_    8
#define L2_   2048
#define K_    16

typedef unsigned int uint;
typedef unsigned short ushort;
typedef unsigned long long u64;
typedef __attribute__((ext_vector_type(8))) short bh8;   // 8 bf16 (4 VGPRs)
typedef __attribute__((ext_vector_type(4))) float f32x4; // MFMA C/D

// round-to-nearest-even f32 -> bf16 (monotone)
__device__ __forceinline__ ushort f2b(float f){
  uint u = __float_as_uint(f);
  return (ushort)((u + 0x7FFFu + ((u >> 16) & 1u)) >> 16);
}
// monotone float->uint mapping (handles tiny negative self-distances)
__device__ __forceinline__ uint ford(float f){
  uint u = __float_as_uint(f);
  return u ^ ((uint)((int)u >> 31) | 0x80000000u);
}
// inverse of ford
__device__ __forceinline__ float unford(uint u){
  uint v = (u & 0x80000000u) ? (u ^ 0x80000000u) : ~u;
  return __uint_as_float(v);
}

__device__ __forceinline__ void ld8(float* t, const float* p){
  float4 a = *(const float4*)p; float4 b = *(const float4*)(p + 4);
  t[0]=a.x; t[1]=a.y; t[2]=a.z; t[3]=a.w; t[4]=b.x; t[5]=b.y; t[6]=b.z; t[7]=b.w;
}
__device__ __forceinline__ bh8 pack8(const float* v){
  bh8 r;
  #pragma unroll
  for (int j = 0; j < 8; ++j) r[j] = (short)f2b(v[j]);
  return r;
}

// ---------------- K0: prep (cF, keep_coords) + weight pre-pack ----------------
// blocks [0,96): pack w1 (8192) + w2 (16384) f32 -> bf16, 1 elem/thread
// blocks [96,352): cF build. blocks [352,544): keep_coords gather.
__global__ __launch_bounds__(256) void prep_pack_k(const float* __restrict__ coords,
                                                   const int* __restrict__ keep,
                                                   const float* __restrict__ w1,
                                                   const float* __restrict__ w2,
                                                   float4* __restrict__ cF,
                                                   float* __restrict__ out0,
                                                   ushort* __restrict__ pw1,
                                                   ushort* __restrict__ pw2){
  int blk = blockIdx.x;
  int tid = threadIdx.x;
  if (blk < 96){
    int e = blk * 256 + tid;                   // e < 24576 = 8192 + 16384
    if (e < 8192) pw1[e] = f2b(w1[e]);
    else          pw2[e - 8192] = f2b(w2[e - 8192]);
  } else if (blk < 352){
    int e = (blk - 96) * 256 + tid;            // e = l*8+n, e < 65536
    int l = e >> 3, n = e & 7;
    const float* cr = coords + (size_t)e * 3;
    float x = cr[0], y = cr[1], z = cr[2];
    float cc;
    {
      #pragma clang fp contract(off)
      cc = x*x + y*y + z*z;                    // matches np sum(c*c,-1): (xx+yy)+zz
    }
    cF[n * L_ + l] = make_float4(x, y, z, cc);
  } else {
    int t = (blk - 352) * 256 + tid;           // t < 49152 = L2*N*3
    int i = t / 24; int rem = t - i * 24;      // (n*3+c)
    out0[t] = coords[(size_t)keep[i] * 24 + rem];
  }
}

// ---------------- K1: MFMA MLP, dim-split 4 ways for occupancy ----------------
// grid 1024, block 256 = 4 waves; block owns 16 rows, wave h owns dims [32h,32h+32).
// 4096 waves -> 4 waves/SIMD (was 1/SIMD): latency hiding for L2 weight loads.
// LN mean/var: per-wave 16-lane shuffle partials + cross-wave LDS sum of 4.
__global__ __launch_bounds__(256) void mlp_k(const float* __restrict__ feat,
                                             const ushort* __restrict__ pw1,
                                             const float* __restrict__ g1,
                                             const float* __restrict__ b1,
                                             const ushort* __restrict__ pw2,
                                             const float* __restrict__ g2,
                                             const float* __restrict__ b2,
                                             uint* __restrict__ fBw){
  __shared__ ushort hlds[16 * 136];            // 4.25 KB: block's 16 rows x 128 dims
  __shared__ float pm1[4][16], pv1[4][16], pm2[4][16], pv2[4][16]; // 1 KB partials
  int tid = threadIdx.x;
  int lane = tid & 63;
  int h = __builtin_amdgcn_readfirstlane(tid >> 6);   // wave = dim quarter
  int quad = lane >> 4, c = lane & 15;
  int rowg = blockIdx.x * 16;                  // block's first row (row = n*2048 + l)

  // A-frags (same 16 rows for all 4 waves): x[rowg+c][s*32 + quad*8 + j]
  bh8 a1[2];
  {
    int rg = rowg + c; int l = rg & 2047, nb = rg >> 11;
    const float* xr = feat + (size_t)((l << 3) + nb) * 64 + quad * 8;
    float t0[8];
    ld8(t0, xr);      a1[0] = pack8(t0);
    ld8(t0, xr + 32); a1[1] = pack8(t0);
  }

  // GEMM1: wave h computes h-dims [32h,32h+32) = 2 MFMA tiles, K=64
  f32x4 acc1[2];
  acc1[0] = (f32x4){0.f,0.f,0.f,0.f}; acc1[1] = (f32x4){0.f,0.f,0.f,0.f};
  #pragma unroll
  for (int s = 0; s < 2; ++s){
    #pragma unroll
    for (int t = 0; t < 2; ++t){
      bh8 wb = *(const bh8*)(pw1 + (size_t)(h * 32 + t * 16 + c) * 64 + s * 32 + quad * 8);
      acc1[t] = __builtin_amdgcn_mfma_f32_16x16x32_bf16(a1[s], wb, acc1[t], 0, 0, 0);
    }
  }

  // LN1: partial sums over this wave's 32 dims, then cross-wave sum of 4
  #pragma unroll
  for (int r = 0; r < 4; ++r){
    float s = acc1[0][r] + acc1[1][r];
    #pragma unroll
    for (int m = 1; m < 16; m <<= 1) s += __shfl_xor(s, m, 16);
    if (c == 0) pm1[h][quad * 4 + r] = s;
  }
  __syncthreads();
  float mean1[4], rstd1[4];
  #pragma unroll
  for (int r = 0; r < 4; ++r){
    int row = quad * 4 + r;
    mean1[r] = (pm1[0][row] + pm1[1][row] + pm1[2][row] + pm1[3][row]) * 0.0078125f;
  }
  #pragma unroll
  for (int r = 0; r < 4; ++r){
    float d0 = acc1[0][r] - mean1[r], d1 = acc1[1][r] - mean1[r];
    float s = d0 * d0 + d1 * d1;
    #pragma unroll
    for (int m = 1; m < 16; m <<= 1) s += __shfl_xor(s, m, 16);
    if (c == 0) pv1[h][quad * 4 + r] = s;
  }
  __syncthreads();
  #pragma unroll
  for (int r = 0; r < 4; ++r){
    int row = quad * 4 + r;
    rstd1[r] = rsqrtf((pv1[0][row] + pv1[1][row] + pv1[2][row] + pv1[3][row]) * 0.0078125f + 1e-5f);
  }
  #pragma unroll
  for (int t = 0; t < 2; ++t){
    int col = h * 32 + t * 16 + c;
    float gv = g1[col], bv = b1[col];
    #pragma unroll
    for (int r = 0; r < 4; ++r){
      float v = (acc1[t][r] - mean1[r]) * rstd1[r] * gv + bv;
      hlds[(quad * 4 + r) * 136 + col] = f2b(v);
    }
  }
  __syncthreads();                             // hl complete for GEMM2 A-reads

  // GEMM2: A = full 128-dim rows from hl, B = wave's 2 dim-tiles of w2
  f32x4 acc2[2];
  acc2[0] = (f32x4){0.f,0.f,0.f,0.f}; acc2[1] = (f32x4){0.f,0.f,0.f,0.f};
  #pragma unroll
  for (int s = 0; s < 4; ++s){
    bh8 af = *(const bh8*)(hlds + c * 136 + s * 32 + quad * 8);   // 16B-aligned
    #pragma unroll
    for (int t = 0; t < 2; ++t){
      bh8 wb = *(const bh8*)(pw2 + (size_t)(h * 32 + t * 16 + c) * 128 + s * 32 + quad * 8);
      acc2[t] = __builtin_amdgcn_mfma_f32_16x16x32_bf16(af, wb, acc2[t], 0, 0, 0);
    }
  }

  // LN2 + ReLU (same cross-wave dance; first sync also fences hl reads before rewrite)
  #pragma unroll
  for (int r = 0; r < 4; ++r){
    float s = acc2[0][r] + acc2[1][r];
    #pragma unroll
    for (int m = 1; m < 16; m <<= 1) s += __shfl_xor(s, m, 16);
    if (c == 0) pm2[h][quad * 4 + r] = s;
  }
  __syncthreads();
  float mean2[4], rstd2[4];
  #pragma unroll
  for (int r = 0; r < 4; ++r){
    int row = quad * 4 + r;
    mean2[r] = (pm2[0][row] + pm2[1][row] + pm2[2][row] + pm2[3][row]) * 0.0078125f;
  }
  #pragma unroll
  for (int r = 0; r < 4; ++r){
    float d0 = acc2[0][r] - mean2[r], d1 = acc2[1][r] - mean2[r];
    float s = d0 * d0 + d1 * d1;
    #pragma unroll
    for (int m = 1; m < 16; m <<= 1) s += __shfl_xor(s, m, 16);
    if (c == 0) pv2[h][quad * 4 + r] = s;
  }
  __syncthreads();
  #pragma unroll
  for (int r = 0; r < 4; ++r){
    int row = quad * 4 + r;
    rstd2[r] = rsqrtf((pv2[0][row] + pv2[1][row] + pv2[2][row] + pv2[3][row]) * 0.0078125f + 1e-5f);
  }
  #pragma unroll
  for (int t = 0; t < 2; ++t){
    int col = h * 32 + t * 16 + c;
    float gv = g2[col], bv = b2[col];
    #pragma unroll
    for (int r = 0; r < 4; ++r){
      float v = fmaxf((acc2[t][r] - mean2[r]) * rstd2[r] * gv + bv, 0.f);
      hlds[(quad * 4 + r) * 136 + col] = f2b(v);
    }
  }
  __syncthreads();                             // hl complete for coop store

  // cooperative coalesced store: 16 rows x 64 dwords, 4 dwords/thread
  // (16 threads/row x uint4 = 64 dwords = all 128 bf16 dims)  [R4 bug: was *2/uint2]
  {
    int row16 = tid >> 4, pos = (tid & 15) * 4;
    const uint* src = (const uint*)hlds + row16 * 68 + pos;
    uint* dst = fBw + (size_t)(rowg + row16) * 64 + pos;
    *(uint4*)dst = *(const uint4*)src;
  }
}

// ---------------- K2: fused KNN + pool, 2 queries per wave (R2-identical) ----------------
__device__ __forceinline__ u64 shfl64(u64 v, int src){
  int lo = __shfl((int)(uint)v, src, 64);
  int hi = __shfl((int)(uint)(v >> 32), src, 64);
  return ((u64)(uint)hi << 32) | (uint)lo;
}

__device__ __forceinline__ u64 bsort64(u64 key, int lane){
  #pragma unroll
  for (int k = 2; k <= 64; k <<= 1){
    #pragma unroll
    for (int j = k >> 1; j > 0; j >>= 1){
      u64 o = shfl64(key, lane ^ j);
      bool lower = (lane & j) == 0;
      bool down  = (lane & k) == 0;
      bool takeMin = (lower == down);
      bool oLess = o < key;
      key = (oLess == takeMin) ? o : key;
    }
  }
  return key;
}
__device__ __forceinline__ u64 bmerge64(u64 key, int lane){
  #pragma unroll
  for (int j = 32; j > 0; j >>= 1){
    u64 o = shfl64(key, lane ^ j);
    bool lower = (lane & j) == 0;
    bool oLess = o < key;
    key = (oLess == lower) ? o : key;
  }
  return key;
}

// exact selection (single instantiation): sort queue (<=128), leave top-16 at
// ldsq[0..16), return the per-lane sorted key (lanes 0..15 = top-16 ascending).
__device__ __attribute__((noinline)) u64 drainx(u64* ldsq, int qcount, int lane){
  u64 a = (lane < qcount) ? ldsq[lane] : ~0ull;
  a = bsort64(a, lane);
  if (qcount > 64){
    u64 b = (64 + lane < qcount) ? ldsq[64 + lane] : ~0ull;
    b = bsort64(b, lane);
    u64 br = shfl64(b, 63 - lane);
    a = a < br ? a : br;
    a = bmerge64(a, lane);
  }
  if (lane < 16) ldsq[lane] = a;
  return a;
}

// Cheap valid bound + compaction, fully inline/unrolled, qc <= 128:
//  - m = per-lane min of the (<=2) stripe entries' high words
//  - 16-step coarse MSB ballot search on bits 31..16: v = largest 2^16-aligned
//    value with count(m < v) < 16;  vb = v + 2^16  =>  vb > true 16th smallest
//    (valid screen/keep upper bound; coarse slack ~2^-7 relative)
//  - compact keeping h <= vb (superset of the true top-16; reuses loaded regs)
//  - cold guard (ties pathology): exact drainx reduce to 16
__device__ __forceinline__ void updq(u64* ql, int& qc, int& nx, float& thr,
                                     float qw, int lane){
  int q = qc;
  u64 k0 = (lane < q) ? ql[lane] : ~0ull;
  u64 k1 = (64 + lane < q) ? ql[64 + lane] : ~0ull;
  uint h0 = (uint)(k0 >> 32), h1 = (uint)(k1 >> 32);
  uint m = h0 < h1 ? h0 : h1;
  uint v = 0u;
  #pragma unroll
  for (int b = 31; b >= 16; --b){
    uint tv = v | (1u << b);
    if (__popcll(__ballot(m < tv)) < 16) v = tv;
  }
  uint vb = (v >= 0xFFFF0000u) ? 0xFFFFFFFFu : (v + 0x10000u);

  bool kp0 = (h0 <= vb);                 // absent lanes: h=0xFFFFFFFF -> dropped
  u64 bal0 = __ballot(kp0);
  int r0 = __builtin_amdgcn_mbcnt_lo((uint)bal0, 0);
  r0 = __builtin_amdgcn_mbcnt_hi((uint)(bal0 >> 32), r0);
  if (kp0) ql[r0] = k0;
  int c0 = __popcll(bal0);
  bool kp1 = (h1 <= vb);
  u64 bal1 = __ballot(kp1);
  int r1 = __builtin_amdgcn_mbcnt_lo((uint)bal1, 0);
  r1 = __builtin_amdgcn_mbcnt_hi((uint)(bal1 >> 32), r1);
  if (kp1) ql[c0 + r1] = k1;
  int out = c0 + __popcll(bal1);

  uint hb = vb;
  if (out > 64){                         // cold: tie pathology -> exact reduce
    u64 a = drainx(ql, out, lane);
    hb = (uint)(shfl64(a, 15) >> 32);
    out = 16;
  }
  qc = out;
  nx = out + 33;
  thr = unford(hb) + 1e-3f - qw;
}

__global__ __launch_bounds__(256) void knn_pool_k(const float4* __restrict__ cF,
                                                  const int* __restrict__ keep,
                                                  const uint* __restrict__ fB32,
                                                  float* __restrict__ out1){
  __shared__ u64 q8[4][2][128];         // 8 KB: 2 survivor queues per wave
  int tid = threadIdx.x, lane = tid & 63;
  int wv = tid >> 6;
  int g0 = blockIdx.x * 8 + wv * 2;     // first query id; block spans 8 queries, one n
  int n = g0 >> 11;
  int i0 = g0 & 2047, i1 = i0 + 1;
  u64* qlA = q8[wv][0];
  u64* qlB = q8[wv][1];
  float4 qa = cF[(n << 13) + keep[i0]];
  float4 qb = cF[(n << 13) + keep[i1]];
  const float4* base = cF + (n << 13);

  // folded screen constants: s(c) = -2*q.c + c.w ; pass iff s <= T - q.w
  float q2ax = -2.f * qa.x, q2ay = -2.f * qa.y, q2az = -2.f * qa.z;
  float q2bx = -2.f * qb.x, q2by = -2.f * qb.y, q2bz = -2.f * qb.z;
  float tA = 3.4e38f, tB = 3.4e38f;
  int qcA = 0, qcB = 0, nxA = 49, nxB = 49;

  #define PROC2(cf, jidx) { \
    float sA = __builtin_fmaf(q2ax,(cf).x, __builtin_fmaf(q2ay,(cf).y, __builtin_fmaf(q2az,(cf).z,(cf).w))); \
    float sB = __builtin_fmaf(q2bx,(cf).x, __builtin_fmaf(q2by,(cf).y, __builtin_fmaf(q2bz,(cf).z,(cf).w))); \
    u64 balA = __ballot(sA <= tA); \
    u64 balB = __ballot(sB <= tB); \
    if (balA){ \
      if (sA <= tA){ \
        float d2; \
        { \
          _Pragma("clang fp contract(off)") \
          float dot = qa.x*(cf).x + qa.y*(cf).y + qa.z*(cf).z; \
          d2 = (qa.w + (cf).w) - 2.0f * dot; \
        } \
        int rel = __builtin_amdgcn_mbcnt_lo((uint)balA, 0); \
        rel = __builtin_amdgcn_mbcnt_hi((uint)(balA >> 32), rel); \
        qlA[qcA + rel] = ((u64)ford(d2) << 32) | (uint)(jidx); \
      } \
      qcA += __popcll(balA); \
      if (qcA >= nxA) updq(qlA, qcA, nxA, tA, qa.w, lane); \
    } \
    if (balB){ \
      if (sB <= tB){ \
        float d2; \
        { \
          _Pragma("clang fp contract(off)") \
          float dot = qb.x*(cf).x + qb.y*(cf).y + qb.z*(cf).z; \
          d2 = (qb.w + (cf).w) - 2.0f * dot; \
        } \
        int rel = __builtin_amdgcn_mbcnt_lo((uint)balB, 0); \
        rel = __builtin_amdgcn_mbcnt_hi((uint)(balB >> 32), rel); \
        qlB[qcB + rel] = ((u64)ford(d2) << 32) | (uint)(jidx); \
      } \
      qcB += __popcll(balB); \
      if (qcB >= nxB) updq(qlB, qcB, nxB, tB, qb.w, lane); \
    } \
  }

  for (int b = 0; b < 128; b += 4){
    const float4* p = base + (b << 6) + lane;
    float4 c0 = p[0];
    float4 c1 = p[64];
    float4 c2 = p[128];
    float4 c3 = p[192];
    int j0 = (b << 6) + lane;
    PROC2(c0, j0);
    PROC2(c1, j0 + 64);
    PROC2(c2, j0 + 128);
    PROC2(c3, j0 + 192);
  }
  #undef PROC2

  // final exact selection (u64 order = (dist, idx) tie-break, matches top_k)
  u64 aA = drainx(qlA, qcA, lane);
  u64 aB = drainx(qlB, qcB, lane);

  const uint* frow = fB32 + ((size_t)(n << 11) << 6);
  float a0 = -3.4e38f, a1v = -3.4e38f, b0 = -3.4e38f, b1v = -3.4e38f;
  #pragma unroll
  for (int k = 0; k < 16; ++k){
    int idxA = (int)(shfl64(aA, k) & 2047u);            // fmod(L2) quirk
    int idxB = (int)(shfl64(aB, k) & 2047u);
    uint uA = frow[((size_t)idxA << 6) + lane];
    uint uB = frow[((size_t)idxB << 6) + lane];
    a0  = fmaxf(a0,  __uint_as_float((uA & 0xFFFFu) << 16));
    a1v = fmaxf(a1v, __uint_as_float((uA >> 16) << 16));
    b0  = fmaxf(b0,  __uint_as_float((uB & 0xFFFFu) << 16));
    b1v = fmaxf(b1v, __uint_as_float((uB >> 16) << 16));
  }
  float2* oA = (float2*)(out1 + (size_t)(i0 * 8 + n) * 128);
  float2* oB = (float2*)(out1 + (size_t)(i1 * 8 + n) * 128);
  oA[lane] = make_float2(a0, a1v);
  oB[lane] = make_float2(b0, b1v);
}

extern "C" void kernel_launch(void* const* d_in, const int* in_sizes, int n_in,
                              void* d_out, int out_size, void* d_ws, size_t ws_size,
                              hipStream_t stream){
  const float* coords = (const float*)d_in[0];
  const float* feat   = (const float*)d_in[1];
  const float* w1     = (const float*)d_in[2];
  const float* g1     = (const float*)d_in[3];
  const float* b1     = (const float*)d_in[4];
  const float* w2     = (const float*)d_in[5];
  const float* g2     = (const float*)d_in[6];
  const float* b2     = (const float*)d_in[7];
  const int*   keep   = (const int*)d_in[8];
  float* out0 = (float*)d_out;                    // keep_coords [2048,8,3]
  float* out1 = out0 + 49152;                     // pool_features [2048,8,128]

  char* ws = (char*)d_ws;
  float4* cF  = (float4*)ws;                      // [N][L] f32x4 : 1 MB
  ushort* fB  = (ushort*)(ws + (1 << 20));        // [N][L2][128] bf16 : 4 MB
  ushort* pw1 = (ushort*)(ws + (5 << 20));        // 16 KB packed w1
  ushort* pw2 = pw1 + 8192;                       // 32 KB packed w2

  hipLaunchKernelGGL(prep_pack_k, dim3(544), dim3(256), 0, stream,
                     coords, keep, w1, w2, cF, out0, pw1, pw2);
  hipLaunchKernelGGL(mlp_k, dim3(1024), dim3(256), 0, stream,
                     feat, pw1, g1, b1, pw2, g2, b2, (uint*)fB);
  hipLaunchKernelGGL(knn_pool_k, dim3(2048), dim3(256), 0, stream,
                     cF, keep, (const uint*)fB, out1);
}